// Round 7
// baseline (498.221 us; speedup 1.0000x reference)
//
#include <hip/hip_runtime.h>

#define N 1024
#define NN (N * N)
#define STRIPS 9           // strips of 128 cols (120 valid): 9*120 = 1080 >= 1024
#define SEGS 128
#define SEGROWS 8
#define WPB 4              // waves per block
#define NWAVES (STRIPS * SEGS * 8)     // 9216 waves
#define NBLOCKS (NWAVES / WPB)         // 2304 blocks of 256 threads

__device__ __forceinline__ int refl(int i) {   // reflect-101
    if (i < 0) return -i;
    if (i >= N) return 2 * N - 2 - i;
    return i;
}
__device__ __forceinline__ float shl(float v, int sl) { return __shfl(v, sl, 64); }

struct F2 { float x, y; };

__device__ __forceinline__ int axcode(float gx, float gy) {
    float ax = fabsf(gx), ay = fabsf(gy);
    return (ay <= 0.41421356f * ax) ? 0
         : (ay >= 2.41421356f * ax) ? 1
         : (((gx > 0.f) == (gy > 0.f)) ? 2 : 3);
}
__device__ __forceinline__ float pick(int code, float r, float u, float ur, float ul) {
    return code == 0 ? r : code == 1 ? u : code == 2 ? ur : ul;
}

#define W0 0.05448868f
#define W1 0.24420134f
#define W2 0.40261996f
#define W3 0.24420134f
#define W4 0.05448868f

struct St {
    F2 h0, h1, h2, h3, h4;          // h-blurred gray rows y-4..y
    F2 bl0, bl1, bl2;               // blurred rows
    F2 mg0, mg1, mg2;               // magnitude rows
    F2 ml0, ml1, ml2;               // magnitude col-left
    F2 mr0, mr1, mr2;               // magnitude col-right
    int ax_x, ax_y;                 // axis of latest sobel row
    int axp_x, axp_y;               // axis of previous sobel row
};

template<bool EC>
__device__ __forceinline__ F2 gray_load(const float* __restrict__ I, int rr,
                                        int c0, int cR0, int cR1)
{
    F2 g;
    if (EC) {
        const float* q0 = I + (size_t)rr * N + cR0;
        const float* q1 = I + (size_t)rr * N + cR1;
        g.x = 0.299f*q0[0] + 0.587f*q0[NN] + 0.114f*q0[2*NN];
        g.y = 0.299f*q1[0] + 0.587f*q1[NN] + 0.114f*q1[2*NN];
    } else {
        const float* p = I + (size_t)rr * N + c0;
        float2 r  = *(const float2*)p;
        float2 gg = *(const float2*)(p + NN);
        float2 bb = *(const float2*)(p + 2 * NN);
        g.x = 0.299f*r.x + 0.587f*gg.x + 0.114f*bb.x;
        g.y = 0.299f*r.y + 0.587f*gg.y + 0.114f*bb.y;
    }
    return g;
}

__device__ __forceinline__ void step_h(St& s, F2 g, int lm, int lp) {
    float gLx = shl(g.x, lm), gLy = shl(g.y, lm);
    float gRx = shl(g.x, lp), gRy = shl(g.y, lp);
    F2 hn;
    hn.x = W0*gLx + W1*gLy + W2*g.x + W3*g.y + W4*gRx;
    hn.y = W0*gLy + W1*g.x + W2*g.y + W3*gRx + W4*gRy;
    s.h0 = s.h1; s.h1 = s.h2; s.h2 = s.h3; s.h3 = s.h4; s.h4 = hn;
}

__device__ __forceinline__ void step_v(St& s) {
    F2 bn;
    bn.x = W0*s.h0.x + W1*s.h1.x + W2*s.h2.x + W3*s.h3.x + W4*s.h4.x;
    bn.y = W0*s.h0.y + W1*s.h1.y + W2*s.h2.y + W3*s.h3.y + W4*s.h4.y;
    s.bl0 = s.bl1; s.bl1 = s.bl2; s.bl2 = bn;
}

template<bool EC>
__device__ __forceinline__ void step_sobel(St& s, bool zT, bool zB,
                                           int lm, int lp, bool p0, bool pN)
{
    F2 b0 = zT ? s.bl1 : s.bl0;
    F2 b2 = zB ? s.bl1 : s.bl2;
    F2 sa, da;
    sa.x = b0.x + 2.f*s.bl1.x + b2.x;  sa.y = b0.y + 2.f*s.bl1.y + b2.y;
    da.x = b2.x - b0.x;                da.y = b2.y - b0.y;
    float sLy = shl(sa.y, lm), sRx = shl(sa.x, lp);
    float dLy = shl(da.y, lm), dRx = shl(da.x, lp);
    if (EC) {
        sLy = p0 ? sa.x : sLy;  dLy = p0 ? da.x : dLy;
        sRx = pN ? sa.y : sRx;  dRx = pN ? da.y : dRx;
    }
    F2 gx, gy;
    gx.x = sa.y - sLy;               gx.y = sRx - sa.x;
    gy.x = dLy + 2.f*da.x + da.y;    gy.y = da.x + 2.f*da.y + dRx;
    F2 mag;
    mag.x = sqrtf(gx.x*gx.x + gy.x*gy.x + 1e-6f);
    mag.y = sqrtf(gx.y*gx.y + gy.y*gy.y + 1e-6f);
    s.axp_x = s.ax_x;  s.axp_y = s.ax_y;
    s.ax_x = axcode(gx.x, gy.x);  s.ax_y = axcode(gx.y, gy.y);
    float mLy = shl(mag.y, lm), mRx = shl(mag.x, lp);
    if (EC) { mLy = p0 ? 0.f : mLy;  mRx = pN ? 0.f : mRx; }
    s.mg0 = s.mg1; s.mg1 = s.mg2; s.mg2 = mag;
    s.ml0 = s.ml1; s.ml1 = s.ml2; s.ml2 = F2{mLy, mag.x};
    s.mr0 = s.mr1; s.mr1 = s.mr2; s.mr2 = F2{mag.y, mRx};
}

__device__ __forceinline__ void nms(const St& s, bool wT, bool wB, bool& ex, bool& ey) {
    F2 up = s.mg0, upL = s.ml0, upR = s.mr0;
    F2 dn = s.mg2, dnL = s.ml2, dnR = s.mr2;
    if (wT) { up = F2{0,0}; upL = F2{0,0}; upR = F2{0,0}; }
    if (wB) { dn = F2{0,0}; dnL = F2{0,0}; dnR = F2{0,0}; }
    float n1x = pick(s.axp_x, s.mr1.x, up.x, upR.x, upL.x);
    float n2x = pick(s.axp_x, s.ml1.x, dn.x, dnL.x, dnR.x);
    float n1y = pick(s.axp_y, s.mr1.y, up.y, upR.y, upL.y);
    float n2y = pick(s.axp_y, s.ml1.y, dn.y, dnL.y, dnR.y);
    ex = (s.mg1.x > n1x) && (s.mg1.x > n2x) && (s.mg1.x > 0.1f);
    ey = (s.mg1.y > n1y) && (s.mg1.y > n2y) && (s.mg1.y > 0.1f);
}

template<bool EC>
__device__ __forceinline__ int strip_seg(const float* __restrict__ A,
                                         const float* __restrict__ B,
                                         int cb, int R0, int lane)
{
    const int c0 = cb + 2 * lane, c1 = c0 + 1;
    const int lm = lane - 1, lp = lane + 1;
    const int cR0 = refl(c0), cR1 = refl(c1);
    const bool p0 = (c0 == 0);
    const bool pN = (c1 == N - 1);
    const bool v0 = (lane >= 2 && lane <= 61 && c0 >= 0 && c0 < N);
    const bool v1 = (lane >= 2 && lane <= 61 && c1 < N);

    St sA{}, sB{};
    int acc = 0;

    // phase 1: y = R0-4 .. R0-1 — gray + h-blur only
#pragma unroll
    for (int k = 0; k < 4; ++k) {
        int rr = refl(R0 - 4 + k);
        step_h(sA, gray_load<EC>(A, rr, c0, cR0, cR1), lm, lp);
        step_h(sB, gray_load<EC>(B, rr, c0, cR0, cR1), lm, lp);
    }
    // phase 2: y = R0, R0+1 — + v-blur
#pragma unroll
    for (int k = 0; k < 2; ++k) {
        int rr = refl(R0 + k);
        step_h(sA, gray_load<EC>(A, rr, c0, cR0, cR1), lm, lp);  step_v(sA);
        step_h(sB, gray_load<EC>(B, rr, c0, cR0, cR1), lm, lp);  step_v(sB);
    }
    // phase 3: y = R0+2, R0+3 — + sobel/mag
#pragma unroll
    for (int k = 0; k < 2; ++k) {
        int y = R0 + 2 + k;
        int rr = refl(y);
        int z = y - 3;
        bool zT = (z == 0), zB = (z == N - 1);
        step_h(sA, gray_load<EC>(A, rr, c0, cR0, cR1), lm, lp);
        step_v(sA);  step_sobel<EC>(sA, zT, zB, lm, lp, p0, pN);
        step_h(sB, gray_load<EC>(B, rr, c0, cR0, cR1), lm, lp);
        step_v(sB);  step_sobel<EC>(sB, zT, zB, lm, lp, p0, pN);
    }
    // phase 4: y = R0+4 .. R0+11 — full pipeline + NMS (w = y-4 = R0..R0+7)
#pragma unroll 4
    for (int k = 0; k < SEGROWS; ++k) {
        int y = R0 + 4 + k;
        int rr = refl(y);
        int z = y - 3, w = y - 4;
        bool zT = (z == 0), zB = (z == N - 1);
        bool wT = (w == 0), wB = (w == N - 1);
        step_h(sA, gray_load<EC>(A, rr, c0, cR0, cR1), lm, lp);
        step_v(sA);  step_sobel<EC>(sA, zT, zB, lm, lp, p0, pN);
        step_h(sB, gray_load<EC>(B, rr, c0, cR0, cR1), lm, lp);
        step_v(sB);  step_sobel<EC>(sB, zT, zB, lm, lp, p0, pN);
        bool eax, eay, ebx, eby;
        nms(sA, wT, wB, eax, eay);
        nms(sB, wT, wB, ebx, eby);
        acc += (int)(v0 && (eax != ebx));
        acc += (int)(v1 && (eay != eby));
    }
    return acc;
}

__global__ __launch_bounds__(256, 8)
void edge_diff_kernel(const float* __restrict__ op, const float* __restrict__ gt,
                      unsigned int* __restrict__ partials)
{
    int lane  = threadIdx.x & 63;
    int gwave = blockIdx.x * WPB + (threadIdx.x >> 6);   // 0..NWAVES-1
    int img   = gwave / (STRIPS * SEGS);
    int rem   = gwave - img * (STRIPS * SEGS);
    int strip = rem / SEGS;
    int seg   = rem - strip * SEGS;

    int cb = strip * 120 - 4;       // valid output cols: cb+4 .. cb+123
    int R0 = seg * SEGROWS;
    const float* A = op + (size_t)img * 3 * NN;
    const float* B = gt + (size_t)img * 3 * NN;

    int acc;
    if (strip == 0 || strip == STRIPS - 1)
        acc = strip_seg<true>(A, B, cb, R0, lane);
    else
        acc = strip_seg<false>(A, B, cb, R0, lane);

    for (int off = 32; off > 0; off >>= 1)
        acc += __shfl_down(acc, off, 64);
    if (lane == 0) partials[gwave] = (unsigned int)acc;
}

__global__ __launch_bounds__(256)
void finalize_kernel(const unsigned int* __restrict__ partials, float* __restrict__ out)
{
    __shared__ unsigned int ws[4];
    int tid = threadIdx.x;
    unsigned int sum = 0;
    for (int i = tid; i < NWAVES; i += 256)
        sum += partials[i];
    int d = (int)sum;
    for (int off = 32; off > 0; off >>= 1)
        d += __shfl_down(d, off, 64);
    if ((tid & 63) == 0) ws[tid >> 6] = (unsigned int)d;
    __syncthreads();
    if (tid == 0)
        out[0] = (float)(ws[0] + ws[1] + ws[2] + ws[3]) / 8388608.0f;  // 8*1024*1024
}

extern "C" void kernel_launch(void* const* d_in, const int* in_sizes, int n_in,
                              void* d_out, int out_size, void* d_ws, size_t ws_size,
                              hipStream_t stream)
{
    const float* op = (const float*)d_in[0];
    const float* gt = (const float*)d_in[1];
    unsigned int* partials = (unsigned int*)d_ws;   // NWAVES uints, fully overwritten

    edge_diff_kernel<<<dim3(NBLOCKS), dim3(256), 0, stream>>>(op, gt, partials);
    finalize_kernel<<<1, dim3(256), 0, stream>>>(partials, (float*)d_out);
}